// Round 1
// 13999.887 us; speedup vs baseline: 1.1844x; 1.1844x over previous
//
#include <hip/hip_runtime.h>
#include <math.h>

#define NB 4
#define NT 1024
#define NO 128
#define NC 512
#define NH 8
#define NL 6
#define NV 32000
#define NHD 64
#define NTK (NT + NO)   // 1152
#define NFF (4 * NC)    // 2048

__device__ __forceinline__ float sigmoidf_(float x) { return 1.f / (1.f + __expf(-x)); }
__device__ __forceinline__ float gelu_(float x) {
    const float k0 = 0.7978845608028654f; // sqrt(2/pi)
    float x3 = x * x * x;
    return 0.5f * x * (1.f + tanhf(k0 * (x + 0.044715f * x3)));
}

// ---------------- Generic fp32 GEMM: out = act(A@W + bias) + res ----------------
// A: (M,K) row-major, W: (K,N) row-major. N % 128 == 0, K % 16 == 0 (true for all calls).
// M may be ragged (guarded). ACT: 0 = none, 1 = tanh-gelu.
// 128x128 block tile, 8x8 per-thread microtile (two 4x4 quads spaced 64 apart).
template <int ACT>
__global__ __launch_bounds__(256) void gemm_kernel(
    const float* __restrict__ A, const float* __restrict__ W,
    const float* __restrict__ bias, const float* __restrict__ res,
    float* __restrict__ out, int M, int N, int K)
{
    __shared__ float As[16][132];
    __shared__ float Bs[16][132];
    int tid = threadIdx.x;
    int bm = blockIdx.y * 128, bn = blockIdx.x * 128;
    int tx = tid & 15, ty = tid >> 4;
    float acc[8][8];
#pragma unroll
    for (int i = 0; i < 8; i++)
#pragma unroll
        for (int j = 0; j < 8; j++) acc[i][j] = 0.f;

    int arow = tid >> 2, akq = (tid & 3) * 4;    // A: rows arow, arow+64; 4 consecutive k
    int bn4 = (tid & 31) * 4, bkk = tid >> 5;    // B: 4 consecutive n; rows bkk, bkk+8

    for (int k0 = 0; k0 < K; k0 += 16) {
        float4 a4[2];
#pragma unroll
        for (int r = 0; r < 2; r++) {
            int gm = bm + arow + 64 * r;
            if (gm < M) a4[r] = *reinterpret_cast<const float4*>(A + (size_t)gm * K + k0 + akq);
            else        a4[r] = make_float4(0.f, 0.f, 0.f, 0.f);
        }
        float4 b4[2];
#pragma unroll
        for (int r = 0; r < 2; r++) {
            int kk = bkk + 8 * r;
            b4[r] = *reinterpret_cast<const float4*>(W + (size_t)(k0 + kk) * N + bn + bn4);
        }
        // previous iteration's trailing barrier protects these writes
#pragma unroll
        for (int r = 0; r < 2; r++) {
            int m = arow + 64 * r;
            As[akq + 0][m] = a4[r].x;
            As[akq + 1][m] = a4[r].y;
            As[akq + 2][m] = a4[r].z;
            As[akq + 3][m] = a4[r].w;
        }
#pragma unroll
        for (int r = 0; r < 2; r++) {
            *reinterpret_cast<float4*>(&Bs[bkk + 8 * r][bn4]) = b4[r];
        }
        __syncthreads();
#pragma unroll
        for (int kk = 0; kk < 16; kk++) {
            float a[8], b[8];
            *reinterpret_cast<float4*>(&a[0]) = *reinterpret_cast<const float4*>(&As[kk][ty * 4]);
            *reinterpret_cast<float4*>(&a[4]) = *reinterpret_cast<const float4*>(&As[kk][ty * 4 + 64]);
            *reinterpret_cast<float4*>(&b[0]) = *reinterpret_cast<const float4*>(&Bs[kk][tx * 4]);
            *reinterpret_cast<float4*>(&b[4]) = *reinterpret_cast<const float4*>(&Bs[kk][tx * 4 + 64]);
#pragma unroll
            for (int i = 0; i < 8; i++)
#pragma unroll
                for (int j = 0; j < 8; j++) acc[i][j] = fmaf(a[i], b[j], acc[i][j]);
        }
        __syncthreads();
    }

#pragma unroll
    for (int i = 0; i < 8; i++) {
        int m = ty * 4 + (i & 3) + ((i & 4) ? 64 : 0);
        int gm = bm + m;
        if (gm >= M) continue;
#pragma unroll
        for (int j = 0; j < 8; j++) {
            int n = tx * 4 + (j & 3) + ((j & 4) ? 64 : 0);
            int gn = bn + n;
            float v = acc[i][j];
            if (bias) v += bias[gn];
            if (ACT == 1) v = gelu_(v);
            if (res) v += res[(size_t)gm * N + gn];
            out[(size_t)gm * N + gn] = v;
        }
    }
}

// ---------------- LayerNorm over C=512, one block per row ----------------
__global__ __launch_bounds__(256) void ln_kernel(
    const float* __restrict__ x, float* __restrict__ y,
    const float* __restrict__ scale, const float* __restrict__ bias)
{
    int row = blockIdx.x, tid = threadIdx.x;
    const float* xr = x + (size_t)row * NC;
    float v0 = xr[tid], v1 = xr[tid + 256];
    __shared__ float red[256];
    red[tid] = v0 + v1;
    __syncthreads();
    for (int s = 128; s > 0; s >>= 1) { if (tid < s) red[tid] += red[tid + s]; __syncthreads(); }
    float mean = red[0] * (1.f / NC);
    __syncthreads();
    float d0 = v0 - mean, d1 = v1 - mean;
    red[tid] = d0 * d0 + d1 * d1;
    __syncthreads();
    for (int s = 128; s > 0; s >>= 1) { if (tid < s) red[tid] += red[tid + s]; __syncthreads(); }
    float rs = rsqrtf(red[0] * (1.f / NC) + 1e-6f);
    float* yr = y + (size_t)row * NC;
    yr[tid] = d0 * rs * scale[tid] + bias[tid];
    yr[tid + 256] = d1 * rs * scale[tid + 256] + bias[tid + 256];
}

// LN over the virtual concat [mem_p (B,O,C), cur (B,T,C)] -> y (B,TK,C)
__global__ __launch_bounds__(256) void lnkv_kernel(
    const float* __restrict__ mem_p, const float* __restrict__ cur,
    float* __restrict__ y, const float* __restrict__ scale, const float* __restrict__ bias)
{
    int row = blockIdx.x;  // b*NTK + r
    int b = row / NTK, r = row % NTK;
    const float* xr = (r < NO) ? (mem_p + (size_t)(b * NO + r) * NC)
                               : (cur + (size_t)(b * NT + (r - NO)) * NC);
    int tid = threadIdx.x;
    float v0 = xr[tid], v1 = xr[tid + 256];
    __shared__ float red[256];
    red[tid] = v0 + v1;
    __syncthreads();
    for (int s = 128; s > 0; s >>= 1) { if (tid < s) red[tid] += red[tid + s]; __syncthreads(); }
    float mean = red[0] * (1.f / NC);
    __syncthreads();
    float d0 = v0 - mean, d1 = v1 - mean;
    red[tid] = d0 * d0 + d1 * d1;
    __syncthreads();
    for (int s = 128; s > 0; s >>= 1) { if (tid < s) red[tid] += red[tid + s]; __syncthreads(); }
    float rs = rsqrtf(red[0] * (1.f / NC) + 1e-6f);
    float* yr = y + (size_t)row * NC;
    yr[tid] = d0 * rs * scale[tid] + bias[tid];
    yr[tid + 256] = d1 * rs * scale[tid + 256] + bias[tid + 256];
}

// ---------------- x = embed[tok] + (ssum@W)[b] * sigmoid(alpha) ----------------
__global__ __launch_bounds__(256) void embed_kernel(
    const int* __restrict__ tokens, const float* __restrict__ emb,
    const float* __restrict__ sp, const float* __restrict__ alpha_gate,
    float* __restrict__ cur)
{
    int idx = blockIdx.x * 256 + threadIdx.x;  // < NB*NT*NC = 2^21
    int c = idx & (NC - 1);
    int t = (idx >> 9) & (NT - 1);
    int b = idx >> 19;
    int tok = tokens[b * NT + t];
    float a = sigmoidf_(alpha_gate[c]);
    cur[idx] = emb[(size_t)tok * NC + c] + sp[b * NC + c] * a;
}

// ---------------- RoPE in place. x: (B, rows, H*HD) ----------------
__global__ __launch_bounds__(256) void rope_kernel(float* __restrict__ x, int rows, int pos_off)
{
    int idx = blockIdx.x * 256 + threadIdx.x;
    int total = NB * rows * NH * 32;
    if (idx >= total) return;
    int j = idx & 31;
    int h = (idx >> 5) & 7;
    int r = (idx >> 8) % rows;
    int b = (idx >> 8) / rows;
    double freq = exp(-(2.0 * j / 64.0) * log(10000.0));
    double ang = (double)(r + pos_off) * freq;
    double sd, cd;
    sincos(ang, &sd, &cd);
    float s = (float)sd, c = (float)cd;
    size_t base = (size_t)((b * rows + r) * NH + h) * NHD + 2 * j;
    float x0 = x[base], x1 = x[base + 1];
    x[base] = x0 * c - x1 * s;
    x[base + 1] = x0 * s + x1 * c;
}

// ---------------- Attention: one block = (b, h, 8 q-rows). ----------------
// QK^T into LDS scores; wave-parallel softmax (wave w owns rows 2w,2w+1, shuffle
// reductions, no barriers, 1/sum kept in registers); PV with 32-row V tiles staged
// in LDS so all 8 q-rows share every V fetch.
__global__ __launch_bounds__(256) void attn_kernel(
    const float* __restrict__ q, const float* __restrict__ k,
    const float* __restrict__ v, const int* __restrict__ tokens,
    float* __restrict__ attn)
{
    __shared__ float qs[8][NHD];      // 2 KB
    __shared__ float sc[8][NTK];      // 36 KB
    __shared__ float vs[32][68];      // 8.5 KB (pad 68: 2-way max on r/w)
    int tid = threadIdx.x;
    int qt = blockIdx.x;  // 0..T/8-1
    int h = blockIdx.y;
    int b = blockIdx.z;
    int t0 = qt * 8;

    for (int idx = tid; idx < 8 * NHD; idx += 256) {
        int qi = idx >> 6, d = idx & 63;
        qs[qi][d] = q[(size_t)(b * NT + t0 + qi) * NC + h * NHD + d];
    }
    __syncthreads();

    // ---- QK^T: thread (qi = tid>>5, lk = tid&31) ----
    const float scale = 0.125f;  // 1/sqrt(64)
    {
        int lk = tid & 31, qi = tid >> 5;
        int t = t0 + qi;
        for (int it = 0; it < NTK / 32; it++) {
            int kk = it * 32 + lk;
            const float4* k4 = reinterpret_cast<const float4*>(k + (size_t)(b * NTK + kk) * NC + h * NHD);
            float s = 0.f;
#pragma unroll
            for (int d4 = 0; d4 < 16; d4++) {
                float4 kv = k4[d4];
                s = fmaf(qs[qi][d4 * 4 + 0], kv.x, s);
                s = fmaf(qs[qi][d4 * 4 + 1], kv.y, s);
                s = fmaf(qs[qi][d4 * 4 + 2], kv.z, s);
                s = fmaf(qs[qi][d4 * 4 + 3], kv.w, s);
            }
            bool valid;
            if (kk < NO) {
                valid = true;
            } else {
                int tk = kk - NO;
                valid = (tk <= t) && (tokens[b * NT + tk] != 0);
            }
            sc[qi][kk] = valid ? s * scale : -1e9f;
        }
    }
    __syncthreads();

    // ---- wave-parallel softmax: wave w handles rows 2w, 2w+1 ----
    int lane = tid & 63, w = tid >> 6;
    float invs[2];
#pragma unroll
    for (int rr = 0; rr < 2; rr++) {
        int r = 2 * w + rr;
        float e[18];
        float m = -3.0e38f;
#pragma unroll
        for (int c = 0; c < 18; c++) { e[c] = sc[r][c * 64 + lane]; m = fmaxf(m, e[c]); }
#pragma unroll
        for (int s = 32; s > 0; s >>= 1) m = fmaxf(m, __shfl_xor(m, s));
        float ssum = 0.f;
#pragma unroll
        for (int c = 0; c < 18; c++) {
            float ev = __expf(e[c] - m);
            sc[r][c * 64 + lane] = ev;   // store unnormalized exp
            ssum += ev;
        }
#pragma unroll
        for (int s = 32; s > 0; s >>= 1) ssum += __shfl_xor(ssum, s);
        invs[rr] = 1.f / ssum;           // wave-uniform, stays in registers
    }

    // ---- PV: wave w -> rows 2w,2w+1; lane = d. V tiled through LDS. ----
    float a0 = 0.f, a1 = 0.f;
    int r0 = 2 * w, r1 = 2 * w + 1;
    int vkk = tid >> 3, vdB = (tid & 7) * 8;   // 32 kk-rows x 64 d, 8 floats/thread
    for (int kt = 0; kt < NTK / 32; kt++) {
        const float* vrow = v + (size_t)(b * NTK + kt * 32 + vkk) * NC + h * NHD + vdB;
        float4 va = *reinterpret_cast<const float4*>(vrow);
        float4 vb = *reinterpret_cast<const float4*>(vrow + 4);
        __syncthreads();   // previous tile fully consumed
        *reinterpret_cast<float4*>(&vs[vkk][vdB]) = va;
        *reinterpret_cast<float4*>(&vs[vkk][vdB + 4]) = vb;
        __syncthreads();
        const float4* p0 = reinterpret_cast<const float4*>(&sc[r0][kt * 32]);
        const float4* p1 = reinterpret_cast<const float4*>(&sc[r1][kt * 32]);
#pragma unroll
        for (int k4 = 0; k4 < 8; k4++) {
            float4 e0 = p0[k4], e1 = p1[k4];
            float v0 = vs[k4 * 4 + 0][lane];
            float v1 = vs[k4 * 4 + 1][lane];
            float v2 = vs[k4 * 4 + 2][lane];
            float v3 = vs[k4 * 4 + 3][lane];
            a0 = fmaf(e0.x, v0, a0); a1 = fmaf(e1.x, v0, a1);
            a0 = fmaf(e0.y, v1, a0); a1 = fmaf(e1.y, v1, a1);
            a0 = fmaf(e0.z, v2, a0); a1 = fmaf(e1.z, v2, a1);
            a0 = fmaf(e0.w, v3, a0); a1 = fmaf(e1.w, v3, a1);
        }
    }
    attn[(size_t)(b * NT + t0 + r0) * NC + h * NHD + lane] = a0 * invs[0];
    attn[(size_t)(b * NT + t0 + r1) * NC + h * NHD + lane] = a1 * invs[1];
}

// ---------------- epilogue helpers ----------------
__global__ __launch_bounds__(256) void newmem_kernel(const float* __restrict__ fin, float* __restrict__ out)
{
    int idx = blockIdx.x * 256 + threadIdx.x;  // < NB*NO*NC = 2^18
    int c = idx & 511;
    int o = (idx >> 9) & 127;
    int b = idx >> 16;
    out[idx] = fin[(size_t)(b * NT + (NT - NO) + o) * NC + c];
}

__global__ __launch_bounds__(256) void masked_kernel(
    const float* __restrict__ fin, const int* __restrict__ tokens, float* __restrict__ out)
{
    int idx = blockIdx.x * 256 + threadIdx.x;  // < NB*NT*NC
    int t = (idx >> 9) & (NT - 1);
    int b = idx >> 19;
    out[idx] = (tokens[b * NT + t] != 0) ? fin[idx] : 0.f;
}

__global__ __launch_bounds__(256) void ssum_kernel(
    const float* __restrict__ masked, const int* __restrict__ tokens,
    const float* __restrict__ ssum_in, const float* __restrict__ lambda_gate,
    float* __restrict__ out)
{
    int idx = blockIdx.x * 256 + threadIdx.x;  // < NB*NC
    int c = idx & 511;
    int b = idx >> 9;
    float sum = 0.f, cnt = 0.f;
    for (int t = 0; t < NT; t++) {
        sum += masked[(size_t)(b * NT + t) * NC + c];
        cnt += (tokens[b * NT + t] != 0) ? 1.f : 0.f;
    }
    float lam = sigmoidf_(lambda_gate[c]);
    out[idx] = ssum_in[idx] * lam + (sum / (cnt + 1e-6f)) * (1.f - lam);
}

extern "C" void kernel_launch(void* const* d_in, const int* in_sizes, int n_in,
                              void* d_out, int out_size, void* d_ws, size_t ws_size,
                              hipStream_t stream)
{
    const int* tokens          = (const int*)d_in[0];
    const float* mem           = (const float*)d_in[1];
    const float* ssum          = (const float*)d_in[2];
    const float* embedw        = (const float*)d_in[3];
    const float* mem_adapter_w = (const float*)d_in[4];
    const float* mem_adapter_b = (const float*)d_in[5];
    const float* mem_norm_s    = (const float*)d_in[6];
    const float* mem_norm_b    = (const float*)d_in[7];
    const float* alpha_gate    = (const float*)d_in[8];
    const float* lambda_gate   = (const float*)d_in[9];
    const float* ssum_proj_w   = (const float*)d_in[10];
    const float* ln1_scale     = (const float*)d_in[11];
    const float* ln1_bias      = (const float*)d_in[12];
    const float* lnkv_scale    = (const float*)d_in[13];
    const float* lnkv_bias     = (const float*)d_in[14];
    const float* q_w           = (const float*)d_in[15];
    const float* q_b           = (const float*)d_in[16];
    const float* k_w           = (const float*)d_in[17];
    const float* k_b           = (const float*)d_in[18];
    const float* v_w           = (const float*)d_in[19];
    const float* v_b           = (const float*)d_in[20];
    const float* o_w           = (const float*)d_in[21];
    const float* o_b           = (const float*)d_in[22];
    const float* ln2_scale     = (const float*)d_in[23];
    const float* ln2_bias      = (const float*)d_in[24];
    const float* mlp_w1        = (const float*)d_in[25];
    const float* mlp_b1        = (const float*)d_in[26];
    const float* mlp_w2        = (const float*)d_in[27];
    const float* mlp_b2        = (const float*)d_in[28];
    const float* final_ln_s    = (const float*)d_in[29];
    const float* final_ln_b    = (const float*)d_in[30];
    const float* out_w         = (const float*)d_in[31];
    const float* out_b         = (const float*)d_in[32];

    // workspace layout (fp32), ~60 MB total with region reuse
    float* w = (float*)d_ws;
    float* cur   = w;                          // B*T*C
    float* nx    = cur + NB * NT * NC;         // B*T*C (also final-LN output)
    float* mem_p = nx + NB * NT * NC;          // B*O*C
    float* nkv   = mem_p + NB * NO * NC;       // B*TK*C
    float* big   = nkv + NB * NTK * NC;        // union region
    float* qb = big;                           // B*T*C
    float* kb = qb + NB * NT * NC;             // B*TK*C
    float* vb = kb + NB * NTK * NC;            // B*TK*C
    float* ab = vb + NB * NTK * NC;            // B*T*C
    float* mlph    = big;                      // B*T*FF (reuses q/k/v/a, dead by then)
    float* maskedb = big;                      // B*T*C  (post-loop)
    float* spb     = big;                      // B*C    (pre-loop)
    float* memtmp  = nkv;                      // B*O*C  (pre-loop, nkv unused yet)

    float* out_mem    = (float*)d_out;                 // B*O*C
    float* out_ssum   = out_mem + NB * NO * NC;        // B*C
    float* out_logits = out_ssum + NB * NC;            // B*T*V

    // --- pre-loop ---
    gemm_kernel<0><<<dim3(NC / 128, 1), 256, 0, stream>>>(ssum, ssum_proj_w, nullptr, nullptr, spb, NB, NC, NC);
    embed_kernel<<<(NB * NT * NC) / 256, 256, 0, stream>>>(tokens, embedw, spb, alpha_gate, cur);
    gemm_kernel<0><<<dim3(NC / 128, (NB * NO) / 128), 256, 0, stream>>>(mem, mem_adapter_w, mem_adapter_b, nullptr, memtmp, NB * NO, NC, NC);
    ln_kernel<<<NB * NO, 256, 0, stream>>>(memtmp, mem_p, mem_norm_s, mem_norm_b);

    // --- layers ---
    for (int l = 0; l < NL; l++) {
        const float* qw = q_w + (size_t)l * NC * NC;
        const float* kw = k_w + (size_t)l * NC * NC;
        const float* vw = v_w + (size_t)l * NC * NC;
        const float* ow = o_w + (size_t)l * NC * NC;
        const float* w1 = mlp_w1 + (size_t)l * NC * NFF;
        const float* w2 = mlp_w2 + (size_t)l * NFF * NC;

        ln_kernel<<<NB * NT, 256, 0, stream>>>(cur, nx, ln1_scale + l * NC, ln1_bias + l * NC);
        lnkv_kernel<<<NB * NTK, 256, 0, stream>>>(mem_p, cur, nkv, lnkv_scale + l * NC, lnkv_bias + l * NC);
        gemm_kernel<0><<<dim3(NC / 128, NB * NT / 128), 256, 0, stream>>>(nx, qw, q_b + l * NC, nullptr, qb, NB * NT, NC, NC);
        gemm_kernel<0><<<dim3(NC / 128, NB * NTK / 128), 256, 0, stream>>>(nkv, kw, k_b + l * NC, nullptr, kb, NB * NTK, NC, NC);
        gemm_kernel<0><<<dim3(NC / 128, NB * NTK / 128), 256, 0, stream>>>(nkv, vw, v_b + l * NC, nullptr, vb, NB * NTK, NC, NC);
        rope_kernel<<<(NB * NT * NH * 32) / 256, 256, 0, stream>>>(qb, NT, NO + 10);
        rope_kernel<<<(NB * NTK * NH * 32) / 256, 256, 0, stream>>>(kb, NTK, 10);
        attn_kernel<<<dim3(NT / 8, NH, NB), 256, 0, stream>>>(qb, kb, vb, tokens, ab);
        gemm_kernel<0><<<dim3(NC / 128, NB * NT / 128), 256, 0, stream>>>(ab, ow, o_b + l * NC, cur, cur, NB * NT, NC, NC);
        ln_kernel<<<NB * NT, 256, 0, stream>>>(cur, nx, ln2_scale + l * NC, ln2_bias + l * NC);
        gemm_kernel<1><<<dim3(NFF / 128, NB * NT / 128), 256, 0, stream>>>(nx, w1, mlp_b1 + l * NFF, nullptr, mlph, NB * NT, NFF, NC);
        gemm_kernel<0><<<dim3(NC / 128, NB * NT / 128), 256, 0, stream>>>(mlph, w2, mlp_b2 + l * NC, cur, cur, NB * NT, NC, NFF);
    }

    // --- epilogue ---
    ln_kernel<<<NB * NT, 256, 0, stream>>>(cur, nx, final_ln_s, final_ln_b);
    newmem_kernel<<<(NB * NO * NC) / 256, 256, 0, stream>>>(nx, out_mem);
    masked_kernel<<<(NB * NT * NC) / 256, 256, 0, stream>>>(nx, tokens, maskedb);
    ssum_kernel<<<(NB * NC) / 256, 256, 0, stream>>>(maskedb, tokens, ssum, lambda_gate, out_ssum);
    gemm_kernel<0><<<dim3(NV / 128, NB * NT / 128), 256, 0, stream>>>(maskedb, out_w, out_b, nullptr, out_logits, NB * NT, NV, NC);
}